// Round 9
// baseline (236.208 us; speedup 1.0000x reference)
//
#include <hip/hip_runtime.h>

#define M_TOK 8192
#define N_OUT 4096
#define K_IN  4096

#define AS1 __attribute__((address_space(1)))
#define AS3 __attribute__((address_space(3)))

typedef __attribute__((ext_vector_type(4))) int i32x4;
typedef __attribute__((ext_vector_type(16))) int i32x16;

// inline-asm ds_read_b128: invisible to compiler AA; ordering is OURS via
// counted lgkmcnt + sched_barrier(0) (rule 18).
template <int OFF>
__device__ __forceinline__ i32x4 dsri(unsigned addr) {
    i32x4 r;
    asm volatile("ds_read_b128 %0, %1 offset:%2" : "=v"(r) : "v"(addr), "n"(OFF));
    return r;
}

__device__ __forceinline__ int pack4(float a, float b, float c, float d, float inv) {
    const int q0 = __float2int_rn(a * inv) & 255;
    const int q1 = __float2int_rn(b * inv) & 255;
    const int q2 = __float2int_rn(c * inv) & 255;
    const int q3 = __float2int_rn(d * inv) & 255;
    return q0 | (q1 << 8) | (q2 << 16) | (q3 << 24);
}

// ------------- prepass 1: per-token absmax quant of x, FRAG-TILED output ------
// Fragment (rb, kf): 1KB contiguous at (rb*128+kf)*1024; byte l*16+j holds
// x[rb*32 + (l&31)][kf*32 + (l>>5)*16 + j] quantized. One block per 32-row
// stripe; phase 1 = row absmax (8 threads/row), phase 2 = quantize+pack in
// OUTPUT order (1KB coalesced writes; reads L2-hot from phase 1).

__global__ __launch_bounds__(256) void quant_x_frag_kernel(
    const float* __restrict__ x, signed char* __restrict__ xqF,
    float* __restrict__ tok_scale)
{
    __shared__ float sm_inv[32];
    const int t = threadIdx.x;
    const int R0 = blockIdx.x * 32;

    // phase 1: absmax of row R0 + (t>>3); 8 threads per row
    {
        const int r = R0 + (t >> 3);
        const float4* xr4 = reinterpret_cast<const float4*>(x) + (size_t)r * 1024;
        float m = 0.f;
        for (int p = 0; p < 128; ++p) {
            const float4 v = xr4[(t & 7) + 8 * p];
            m = fmaxf(m, fmaxf(fmaxf(fabsf(v.x), fabsf(v.y)),
                               fmaxf(fabsf(v.z), fabsf(v.w))));
        }
        m = fmaxf(m, __shfl_xor(m, 1, 64));
        m = fmaxf(m, __shfl_xor(m, 2, 64));
        m = fmaxf(m, __shfl_xor(m, 4, 64));
        if ((t & 7) == 0) {
            sm_inv[t >> 3] = (m > 0.f) ? (127.0f / m) : 0.f;
            tok_scale[r] = m * (1.0f / 127.0f);
        }
    }
    __syncthreads();

    // phase 2: warp W emits frags f = W + 4p; lane l covers row (l&31),
    // 16 k-consecutive values at kf*32 + (l>>5)*16.
    const int l = t & 63;
    const int W = t >> 6;
    const int r = R0 + (l & 31);
    const float inv = sm_inv[l & 31];
    const float4* xr4 = reinterpret_cast<const float4*>(x) + (size_t)r * 1024;
    i32x4* outF = reinterpret_cast<i32x4*>(xqF) + (size_t)blockIdx.x * 128 * 64 + l;
#pragma unroll 4
    for (int p = 0; p < 32; ++p) {
        const int f = W + 4 * p;
        const int c4 = f * 8 + (l >> 5) * 4;
        const float4 v0 = xr4[c4 + 0];
        const float4 v1 = xr4[c4 + 1];
        const float4 v2 = xr4[c4 + 2];
        const float4 v3 = xr4[c4 + 3];
        i32x4 o;
        o[0] = pack4(v0.x, v0.y, v0.z, v0.w, inv);
        o[1] = pack4(v1.x, v1.y, v1.z, v1.w, inv);
        o[2] = pack4(v2.x, v2.y, v2.z, v2.w, inv);
        o[3] = pack4(v3.x, v3.y, v3.z, v3.w, inv);
        outF[(size_t)f * 64] = o;
    }
}

// ------------- prepass 2: pack Wq int32 -> int8, FRAG-TILED output ------------

__global__ __launch_bounds__(256) void pack_w_frag_kernel(
    const int* __restrict__ wq, signed char* __restrict__ wqF)
{
    const int t = threadIdx.x;
    const int l = t & 63;
    const int W = t >> 6;
    const int R0 = blockIdx.x * 32;
    const int r = R0 + (l & 31);
    const int4* wr4 = reinterpret_cast<const int4*>(wq) + (size_t)r * 1024;
    i32x4* outF = reinterpret_cast<i32x4*>(wqF) + (size_t)blockIdx.x * 128 * 64 + l;
#pragma unroll 4
    for (int p = 0; p < 32; ++p) {
        const int f = W + 4 * p;
        const int c4 = f * 8 + (l >> 5) * 4;
        i32x4 o;
#pragma unroll
        for (int j = 0; j < 4; ++j) {
            const int4 a = wr4[c4 + j];
            o[j] = (a.x & 255) | ((a.y & 255) << 8) | ((a.z & 255) << 16) | ((a.w & 255) << 24);
        }
        outF[(size_t)f * 64] = o;
    }
}

// ------- int8 GEMM: 256x256 tile, BK=64, 8 waves, mfma_i32_32x32x32_i8 -------
// C = Xq[M,K]*Wq8[N,K]^T (i32 acc); out = acc*ts[row]*(rs[col]/127)+bias.
// FRAGMENT-LINEAR LDS (0 bank conflicts, R7-verified) + R9: FRAG-TILED GLOBAL
// layout -> every global_load_lds source is 1KB CONTIGUOUS (8x128B lines,
// full-width LDS writes) instead of a 32-row x 32B gather. ds_read side and
// sync skeleton unchanged from R8 (full-body lookahead, ring-4, one barrier).

#define BKB 64
#define NKT (K_IN / BKB)   // 64
#define SLOT 32768
#define NSLOT 4

#define MFMA(a, b, c) c = __builtin_amdgcn_mfma_i32_32x32x32_i8(a, b, c, 0, 0, 0)

#define RD12(P, aB, bB)                        \
    P##_A0 = dsri<0>(aB);                      \
    P##_A1 = dsri<2048>(aB);                   \
    P##_A2 = dsri<4096>(aB);                   \
    P##_A3 = dsri<6144>(aB);                   \
    P##_B0 = dsri<0>(bB);                      \
    P##_B1 = dsri<2048>(bB);                   \
    P##_A4 = dsri<1024>(aB);                   \
    P##_A5 = dsri<3072>(aB);                   \
    P##_A6 = dsri<5120>(aB);                   \
    P##_A7 = dsri<7168>(aB);                   \
    P##_B2 = dsri<1024>(bB);                   \
    P##_B3 = dsri<3072>(bB);

#define CL8_0(P)                                              \
    MFMA(P##_A0, P##_B0, acc00); MFMA(P##_A0, P##_B1, acc01); \
    MFMA(P##_A1, P##_B0, acc10); MFMA(P##_A1, P##_B1, acc11); \
    MFMA(P##_A2, P##_B0, acc20); MFMA(P##_A2, P##_B1, acc21); \
    MFMA(P##_A3, P##_B0, acc30); MFMA(P##_A3, P##_B1, acc31);

#define CL8_1(P)                                              \
    MFMA(P##_A4, P##_B2, acc00); MFMA(P##_A4, P##_B3, acc01); \
    MFMA(P##_A5, P##_B2, acc10); MFMA(P##_A5, P##_B3, acc11); \
    MFMA(P##_A6, P##_B2, acc20); MFMA(P##_A6, P##_B3, acc21); \
    MFMA(P##_A7, P##_B2, acc30); MFMA(P##_A7, P##_B3, acc31);

#define GBODY(T, C, N, DO_STAGE)                                          \
    {                                                                     \
        asm volatile("s_waitcnt lgkmcnt(6)" ::: "memory");                \
        __builtin_amdgcn_sched_barrier(0);                                \
        __builtin_amdgcn_s_setprio(1);                                    \
        CL8_0(C)                                                          \
        __builtin_amdgcn_s_setprio(0);                                    \
        __builtin_amdgcn_sched_barrier(0);                                \
        const unsigned aN_ = aBase + (unsigned)((((T) + 1) & 3) * SLOT);  \
        const unsigned bN_ = bBase + (unsigned)((((T) + 1) & 3) * SLOT);  \
        RD12(N, aN_, bN_)                                                 \
        if (DO_STAGE) stageAB((T) + 3);                                   \
        asm volatile("s_waitcnt lgkmcnt(12)" ::: "memory");               \
        __builtin_amdgcn_sched_barrier(0);                                \
        __builtin_amdgcn_s_setprio(1);                                    \
        CL8_1(C)                                                          \
        __builtin_amdgcn_s_setprio(0);                                    \
        __builtin_amdgcn_sched_barrier(0);                                \
        if (DO_STAGE) { asm volatile("s_waitcnt vmcnt(4)" ::: "memory"); }\
        else          { asm volatile("s_waitcnt vmcnt(0)" ::: "memory"); }\
        __builtin_amdgcn_sched_barrier(0);                                \
        __builtin_amdgcn_s_barrier();                                     \
        __builtin_amdgcn_sched_barrier(0);                                \
    }

#define GFINAL(C)                                                         \
    {                                                                     \
        asm volatile("s_waitcnt lgkmcnt(6)" ::: "memory");                \
        __builtin_amdgcn_sched_barrier(0);                                \
        __builtin_amdgcn_s_setprio(1);                                    \
        CL8_0(C)                                                          \
        __builtin_amdgcn_s_setprio(0);                                    \
        asm volatile("s_waitcnt lgkmcnt(0)" ::: "memory");                \
        __builtin_amdgcn_sched_barrier(0);                                \
        __builtin_amdgcn_s_setprio(1);                                    \
        CL8_1(C)                                                          \
        __builtin_amdgcn_s_setprio(0);                                    \
        __builtin_amdgcn_sched_barrier(0);                                \
    }

__global__ __launch_bounds__(512, 2) void qgemm_i8f_kernel(
    const signed char* __restrict__ xqF,
    const signed char* __restrict__ wqF,
    const float* __restrict__ tok_scale,
    const float* __restrict__ row_scales,
    const float* __restrict__ bias,
    float* __restrict__ out)
{
    __shared__ __align__(16) char smem[NSLOT * SLOT + 1024];  // 129 KiB

    const int tid = threadIdx.x;
    const int l = tid & 63;
    const int w = tid >> 6;      // 0..7
    const int wr = w >> 2;       // 0..1
    const int wc = w & 3;        // 0..3

    // XCD-aware bijective swizzle (nwg = 512, 512 % 8 == 0)
    const int bid = blockIdx.x;
    const int swz = (bid & 7) * 64 + (bid >> 3);
    const int bm = swz >> 4;     // 0..31
    const int bn = swz & 15;     // 0..15

    // ---- staging: wave w stages A row-block bm*8+w, B row-block bn*8+w ----
    // frag-tiled global: frag (rb, kf) at (rb*128 + kf)*1024 + lane*16.
    const signed char* aS = xqF + ((size_t)(bm * 8 + w) * 128) * 1024 + (size_t)l * 16;
    const signed char* bS = wqF + ((size_t)(bn * 8 + w) * 128) * 1024 + (size_t)l * 16;
    char* aDst = smem + w * 2048;              // A region [0,16K) of slot
    char* bDst = smem + 16384 + w * 2048;      // B region [16K,32K) of slot

    auto stageAB = [&](int tt) {
        const int sb = (tt & 3) * SLOT;
        const signed char* a0 = aS + (size_t)tt * 2048;   // frags t*2, t*2+1
        const signed char* b0 = bS + (size_t)tt * 2048;
        __builtin_amdgcn_global_load_lds((const AS1 void*)a0,          (AS3 void*)(aDst + sb),        16, 0, 0);
        __builtin_amdgcn_global_load_lds((const AS1 void*)(a0 + 1024), (AS3 void*)(aDst + sb + 1024), 16, 0, 0);
        __builtin_amdgcn_global_load_lds((const AS1 void*)b0,          (AS3 void*)(bDst + sb),        16, 0, 0);
        __builtin_amdgcn_global_load_lds((const AS1 void*)(b0 + 1024), (AS3 void*)(bDst + sb + 1024), 16, 0, 0);
    };

    // ---- fragment-linear ds_read bases ----
    const unsigned sbase = (unsigned)(uintptr_t)(AS3 char*)smem;
    const unsigned aBase = sbase + (unsigned)(wr * 8192 + l * 16);           // + slot + (mb*2+kh)*1024
    const unsigned bBase = sbase + 16384u + (unsigned)(wc * 4096 + l * 16);  // + slot + (nb*2+kh)*1024

    i32x16 acc00 = {0}, acc01 = {0}, acc10 = {0}, acc11 = {0};
    i32x16 acc20 = {0}, acc21 = {0}, acc30 = {0}, acc31 = {0};

    i32x4 X_A0, X_A1, X_A2, X_A3, X_A4, X_A5, X_A6, X_A7, X_B0, X_B1, X_B2, X_B3;
    i32x4 Y_A0, Y_A1, Y_A2, Y_A3, Y_A4, Y_A5, Y_A6, Y_A7, Y_B0, Y_B1, Y_B2, Y_B3;

    // ---- prologue: stage tiles 0,1,2; confirm 0,1; read ALL of tile 0 ----
    stageAB(0); stageAB(1); stageAB(2);
    asm volatile("s_waitcnt vmcnt(4)" ::: "memory");
    __builtin_amdgcn_sched_barrier(0);
    __builtin_amdgcn_s_barrier();
    __builtin_amdgcn_sched_barrier(0);
    RD12(X, aBase, bBase)

    // ---- main loop: bodies 0..62 (X/Y alternate), body 63 = final ----
    for (int t = 0; t < 62; t += 2) {
        GBODY(t,     X, Y, (t + 3 < NKT));
        GBODY(t + 1, Y, X, (t + 4 < NKT));
    }
    GBODY(62, X, Y, false);
    GFINAL(Y)

    // ---- epilogue: tok scales via LDS, dequant, store ----
    float* ts = (float*)(smem + NSLOT * SLOT);
    if (tid < 256) ts[tid] = tok_scale[bm * 256 + tid];
    __syncthreads();

    const int cl = l & 31;
    const int rg4 = (l >> 5) * 4;
    const int gcol0 = bn * 256 + wc * 64;
    float cs[2], bb[2];
#pragma unroll
    for (int nb = 0; nb < 2; ++nb) {
        const int col = gcol0 + nb * 32 + cl;
        cs[nb] = row_scales[col] * (1.0f / 127.0f);
        bb[nb] = bias[col];
    }
    const i32x16* accs[4][2] = {{&acc00, &acc01}, {&acc10, &acc11},
                                {&acc20, &acc21}, {&acc30, &acc31}};
#pragma unroll
    for (int mb = 0; mb < 4; ++mb) {
#pragma unroll
        for (int reg = 0; reg < 16; ++reg) {
            const int rloc = wr * 128 + mb * 32 + (reg & 3) + 8 * (reg >> 2) + rg4;
            const float tsv = ts[rloc];
            float* orow = out + (size_t)(bm * 256 + rloc) * N_OUT + gcol0 + cl;
#pragma unroll
            for (int nb = 0; nb < 2; ++nb) {
                const int a = (*accs[mb][nb])[reg];
                orow[nb * 32] = (float)a * tsv * cs[nb] + bb[nb];
            }
        }
    }
}

// ---------------- launch ----------------

extern "C" void kernel_launch(void* const* d_in, const int* in_sizes, int n_in,
                              void* d_out, int out_size, void* d_ws, size_t ws_size,
                              hipStream_t stream) {
    const float* x = (const float*)d_in[0];
    const int* wq = (const int*)d_in[1];
    const float* row_scales = (const float*)d_in[2];
    const float* bias = (const float*)d_in[3];
    float* out = (float*)d_out;

    signed char* xqF = (signed char*)d_ws;                       // 32 MiB (frag-tiled)
    signed char* wqF = xqF + (size_t)M_TOK * K_IN;               // 16 MiB (frag-tiled)
    float* tok_scale = (float*)(wqF + (size_t)N_OUT * K_IN);     // 32 KiB
    (void)ws_size;

    quant_x_frag_kernel<<<M_TOK / 32, 256, 0, stream>>>(x, xqF, tok_scale);
    pack_w_frag_kernel<<<N_OUT / 32, 256, 0, stream>>>(wq, wqF);

    const int nblocks = (M_TOK / 256) * (N_OUT / 256);  // 512
    qgemm_i8f_kernel<<<nblocks, 512, 0, stream>>>(
        xqF, wqF, tok_scale, row_scales, bias, out);
}

// Round 10
// 192.105 us; speedup vs baseline: 1.2296x; 1.2296x over previous
//
#include <hip/hip_runtime.h>

#define M_TOK 8192
#define N_OUT 4096
#define K_IN  4096

#define AS1 __attribute__((address_space(1)))
#define AS3 __attribute__((address_space(3)))

typedef __attribute__((ext_vector_type(4))) int i32x4;
typedef __attribute__((ext_vector_type(16))) int i32x16;

// inline-asm ds_read_b128: invisible to compiler AA; ordering is OURS via
// counted lgkmcnt + sched_barrier(0) (rule 18).
template <int OFF>
__device__ __forceinline__ i32x4 dsri(unsigned addr) {
    i32x4 r;
    asm volatile("ds_read_b128 %0, %1 offset:%2" : "=v"(r) : "v"(addr), "n"(OFF));
    return r;
}

// ---------------- prepass 1: per-token absmax quant of x (row-major out) ----
// One block per row; whole row register-resident -> single pass. 8192 blocks.

__global__ __launch_bounds__(256) void quant_x_kernel(
    const float* __restrict__ x, signed char* __restrict__ xq,
    float* __restrict__ tok_scale)
{
    const int row = blockIdx.x;
    const float4* xr = reinterpret_cast<const float4*>(x + (size_t)row * K_IN);
    const int t = threadIdx.x;
    float4 v[4];
    float m = 0.f;
#pragma unroll
    for (int i = 0; i < 4; ++i) {
        v[i] = xr[t + 256 * i];
        m = fmaxf(m, fmaxf(fmaxf(fabsf(v[i].x), fabsf(v[i].y)),
                           fmaxf(fabsf(v[i].z), fabsf(v[i].w))));
    }
#pragma unroll
    for (int off = 32; off >= 1; off >>= 1)
        m = fmaxf(m, __shfl_xor(m, off, 64));
    __shared__ float wmax[4];
    if ((t & 63) == 0) wmax[t >> 6] = m;
    __syncthreads();
    m = fmaxf(fmaxf(wmax[0], wmax[1]), fmaxf(wmax[2], wmax[3]));
    if (t == 0) tok_scale[row] = m * (1.0f / 127.0f);
    const float inv = (m > 0.f) ? (127.0f / m) : 0.f;
    int* xqi = reinterpret_cast<int*>(xq + (size_t)row * K_IN);
#pragma unroll
    for (int i = 0; i < 4; ++i) {
        const int q0 = __float2int_rn(v[i].x * inv) & 255;
        const int q1 = __float2int_rn(v[i].y * inv) & 255;
        const int q2 = __float2int_rn(v[i].z * inv) & 255;
        const int q3 = __float2int_rn(v[i].w * inv) & 255;
        xqi[t + 256 * i] = q0 | (q1 << 8) | (q2 << 16) | (q3 << 24);
    }
}

// ---------------- prepass 1b: retile xq8 row-major -> frag-tiled -------------
// Frag (rb,kf): 1KB at (rb*128+kf)*1024; byte l*16+j = xq8[rb*32+(l&31)]
// [kf*32+(l>>5)*16+j]. Block = 32 rows x 1024 cols chunk (32KB LDS), 1024
// blocks (4/CU). Coalesced reads -> XOR-swizzled LDS -> 1KB/wave frag writes.

__global__ __launch_bounds__(256) void retile_x_kernel(
    const signed char* __restrict__ xq8, signed char* __restrict__ xqF)
{
    __shared__ __align__(16) char lds[32768];
    const int t = threadIdx.x;
    const int rb = blockIdx.x >> 2;
    const int kc = blockIdx.x & 3;

    // stage: 2048 int4 units; unit u -> row u>>6, granule u&63 (coalesced)
    const size_t srcBase = (size_t)rb * 32 * K_IN + (size_t)kc * 1024;
#pragma unroll
    for (int j = 0; j < 8; ++j) {
        const int u = j * 256 + t;
        const int row = u >> 6, gc = u & 63;
        const i32x4 v = *reinterpret_cast<const i32x4*>(
            xq8 + srcBase + (size_t)row * K_IN + gc * 16);
        *reinterpret_cast<i32x4*>(
            lds + ((row * 64 + (gc ^ (row & 7))) * 16)) = v;
    }
    __syncthreads();

    // emit: wave W builds frags kfl = W*8+i; lane l: row l&31, gc kfl*2+(l>>5)
    const int l = t & 63;
    const int W = t >> 6;
    const int row = l & 31;
    const int hi = l >> 5;
    i32x4* dst0 = reinterpret_cast<i32x4*>(xqF) +
                  ((size_t)rb * 128 + kc * 32) * 64 + l;
#pragma unroll
    for (int i = 0; i < 8; ++i) {
        const int kfl = W * 8 + i;
        const int gc = (kfl * 2 + hi) ^ (row & 7);
        const i32x4 v = *reinterpret_cast<const i32x4*>(
            lds + ((row * 64 + gc) * 16));
        dst0[(size_t)kfl * 64] = v;
    }
}

// ---------------- prepass 2: pack Wq int32 -> int8, frag-tiled ---------------
// 1024 blocks (rb 128 x pc 8); each block does 4 of 32 p-iterations.

__global__ __launch_bounds__(256) void pack_w_frag_kernel(
    const int* __restrict__ wq, signed char* __restrict__ wqF)
{
    const int t = threadIdx.x;
    const int l = t & 63;
    const int W = t >> 6;
    const int rb = blockIdx.x >> 3;
    const int pc = blockIdx.x & 7;
    const int r = rb * 32 + (l & 31);
    const int4* wr4 = reinterpret_cast<const int4*>(wq) + (size_t)r * 1024;
    i32x4* outF = reinterpret_cast<i32x4*>(wqF) + (size_t)rb * 128 * 64 + l;
#pragma unroll
    for (int q = 0; q < 4; ++q) {
        const int f = W + 4 * (pc * 4 + q);
        const int c4 = f * 8 + (l >> 5) * 4;
        i32x4 o;
#pragma unroll
        for (int j = 0; j < 4; ++j) {
            const int4 a = wr4[c4 + j];
            o[j] = (a.x & 255) | ((a.y & 255) << 8) | ((a.z & 255) << 16) | ((a.w & 255) << 24);
        }
        outF[(size_t)f * 64] = o;
    }
}

// ------- int8 GEMM: 256x256 tile, BK=64, 8 waves, mfma_i32_32x32x32_i8 -------
// UNCHANGED from R9 (135 us, MfmaUtil ~48, 0 bank conflicts).
// Fragment-linear LDS + frag-tiled global; full-body read lookahead; ring-4;
// one barrier per tile; counted vmcnt/lgkmcnt.

#define BKB 64
#define NKT (K_IN / BKB)   // 64
#define SLOT 32768
#define NSLOT 4

#define MFMA(a, b, c) c = __builtin_amdgcn_mfma_i32_32x32x32_i8(a, b, c, 0, 0, 0)

#define RD12(P, aB, bB)                        \
    P##_A0 = dsri<0>(aB);                      \
    P##_A1 = dsri<2048>(aB);                   \
    P##_A2 = dsri<4096>(aB);                   \
    P##_A3 = dsri<6144>(aB);                   \
    P##_B0 = dsri<0>(bB);                      \
    P##_B1 = dsri<2048>(bB);                   \
    P##_A4 = dsri<1024>(aB);                   \
    P##_A5 = dsri<3072>(aB);                   \
    P##_A6 = dsri<5120>(aB);                   \
    P##_A7 = dsri<7168>(aB);                   \
    P##_B2 = dsri<1024>(bB);                   \
    P##_B3 = dsri<3072>(bB);

#define CL8_0(P)                                              \
    MFMA(P##_A0, P##_B0, acc00); MFMA(P##_A0, P##_B1, acc01); \
    MFMA(P##_A1, P##_B0, acc10); MFMA(P##_A1, P##_B1, acc11); \
    MFMA(P##_A2, P##_B0, acc20); MFMA(P##_A2, P##_B1, acc21); \
    MFMA(P##_A3, P##_B0, acc30); MFMA(P##_A3, P##_B1, acc31);

#define CL8_1(P)                                              \
    MFMA(P##_A4, P##_B2, acc00); MFMA(P##_A4, P##_B3, acc01); \
    MFMA(P##_A5, P##_B2, acc10); MFMA(P##_A5, P##_B3, acc11); \
    MFMA(P##_A6, P##_B2, acc20); MFMA(P##_A6, P##_B3, acc21); \
    MFMA(P##_A7, P##_B2, acc30); MFMA(P##_A7, P##_B3, acc31);

#define GBODY(T, C, N, DO_STAGE)                                          \
    {                                                                     \
        asm volatile("s_waitcnt lgkmcnt(6)" ::: "memory");                \
        __builtin_amdgcn_sched_barrier(0);                                \
        __builtin_amdgcn_s_setprio(1);                                    \
        CL8_0(C)                                                          \
        __builtin_amdgcn_s_setprio(0);                                    \
        __builtin_amdgcn_sched_barrier(0);                                \
        const unsigned aN_ = aBase + (unsigned)((((T) + 1) & 3) * SLOT);  \
        const unsigned bN_ = bBase + (unsigned)((((T) + 1) & 3) * SLOT);  \
        RD12(N, aN_, bN_)                                                 \
        if (DO_STAGE) stageAB((T) + 3);                                   \
        asm volatile("s_waitcnt lgkmcnt(12)" ::: "memory");               \
        __builtin_amdgcn_sched_barrier(0);                                \
        __builtin_amdgcn_s_setprio(1);                                    \
        CL8_1(C)                                                          \
        __builtin_amdgcn_s_setprio(0);                                    \
        __builtin_amdgcn_sched_barrier(0);                                \
        if (DO_STAGE) { asm volatile("s_waitcnt vmcnt(4)" ::: "memory"); }\
        else          { asm volatile("s_waitcnt vmcnt(0)" ::: "memory"); }\
        __builtin_amdgcn_sched_barrier(0);                                \
        __builtin_amdgcn_s_barrier();                                     \
        __builtin_amdgcn_sched_barrier(0);                                \
    }

#define GFINAL(C)                                                         \
    {                                                                     \
        asm volatile("s_waitcnt lgkmcnt(6)" ::: "memory");                \
        __builtin_amdgcn_sched_barrier(0);                                \
        __builtin_amdgcn_s_setprio(1);                                    \
        CL8_0(C)                                                          \
        __builtin_amdgcn_s_setprio(0);                                    \
        asm volatile("s_waitcnt lgkmcnt(0)" ::: "memory");                \
        __builtin_amdgcn_sched_barrier(0);                                \
        __builtin_amdgcn_s_setprio(1);                                    \
        CL8_1(C)                                                          \
        __builtin_amdgcn_s_setprio(0);                                    \
        __builtin_amdgcn_sched_barrier(0);                                \
    }

__global__ __launch_bounds__(512, 2) void qgemm_i8f_kernel(
    const signed char* __restrict__ xqF,
    const signed char* __restrict__ wqF,
    const float* __restrict__ tok_scale,
    const float* __restrict__ row_scales,
    const float* __restrict__ bias,
    float* __restrict__ out)
{
    __shared__ __align__(16) char smem[NSLOT * SLOT + 1024];  // 129 KiB

    const int tid = threadIdx.x;
    const int l = tid & 63;
    const int w = tid >> 6;      // 0..7
    const int wr = w >> 2;       // 0..1
    const int wc = w & 3;        // 0..3

    // XCD-aware bijective swizzle (nwg = 512, 512 % 8 == 0)
    const int bid = blockIdx.x;
    const int swz = (bid & 7) * 64 + (bid >> 3);
    const int bm = swz >> 4;     // 0..31
    const int bn = swz & 15;     // 0..15

    // ---- staging: wave w stages A row-block bm*8+w, B row-block bn*8+w ----
    const signed char* aS = xqF + ((size_t)(bm * 8 + w) * 128) * 1024 + (size_t)l * 16;
    const signed char* bS = wqF + ((size_t)(bn * 8 + w) * 128) * 1024 + (size_t)l * 16;
    char* aDst = smem + w * 2048;              // A region [0,16K) of slot
    char* bDst = smem + 16384 + w * 2048;      // B region [16K,32K) of slot

    auto stageAB = [&](int tt) {
        const int sb = (tt & 3) * SLOT;
        const signed char* a0 = aS + (size_t)tt * 2048;   // frags t*2, t*2+1
        const signed char* b0 = bS + (size_t)tt * 2048;
        __builtin_amdgcn_global_load_lds((const AS1 void*)a0,          (AS3 void*)(aDst + sb),        16, 0, 0);
        __builtin_amdgcn_global_load_lds((const AS1 void*)(a0 + 1024), (AS3 void*)(aDst + sb + 1024), 16, 0, 0);
        __builtin_amdgcn_global_load_lds((const AS1 void*)b0,          (AS3 void*)(bDst + sb),        16, 0, 0);
        __builtin_amdgcn_global_load_lds((const AS1 void*)(b0 + 1024), (AS3 void*)(bDst + sb + 1024), 16, 0, 0);
    };

    // ---- fragment-linear ds_read bases ----
    const unsigned sbase = (unsigned)(uintptr_t)(AS3 char*)smem;
    const unsigned aBase = sbase + (unsigned)(wr * 8192 + l * 16);           // + slot + (mb*2+kh)*1024
    const unsigned bBase = sbase + 16384u + (unsigned)(wc * 4096 + l * 16);  // + slot + (nb*2+kh)*1024

    i32x16 acc00 = {0}, acc01 = {0}, acc10 = {0}, acc11 = {0};
    i32x16 acc20 = {0}, acc21 = {0}, acc30 = {0}, acc31 = {0};

    i32x4 X_A0, X_A1, X_A2, X_A3, X_A4, X_A5, X_A6, X_A7, X_B0, X_B1, X_B2, X_B3;
    i32x4 Y_A0, Y_A1, Y_A2, Y_A3, Y_A4, Y_A5, Y_A6, Y_A7, Y_B0, Y_B1, Y_B2, Y_B3;

    // ---- prologue: stage tiles 0,1,2; confirm 0,1; read ALL of tile 0 ----
    stageAB(0); stageAB(1); stageAB(2);
    asm volatile("s_waitcnt vmcnt(4)" ::: "memory");
    __builtin_amdgcn_sched_barrier(0);
    __builtin_amdgcn_s_barrier();
    __builtin_amdgcn_sched_barrier(0);
    RD12(X, aBase, bBase)

    // ---- main loop: bodies 0..62 (X/Y alternate), body 63 = final ----
    for (int t = 0; t < 62; t += 2) {
        GBODY(t,     X, Y, (t + 3 < NKT));
        GBODY(t + 1, Y, X, (t + 4 < NKT));
    }
    GBODY(62, X, Y, false);
    GFINAL(Y)

    // ---- epilogue: tok scales via LDS, dequant, store ----
    float* ts = (float*)(smem + NSLOT * SLOT);
    if (tid < 256) ts[tid] = tok_scale[bm * 256 + tid];
    __syncthreads();

    const int cl = l & 31;
    const int rg4 = (l >> 5) * 4;
    const int gcol0 = bn * 256 + wc * 64;
    float cs[2], bb[2];
#pragma unroll
    for (int nb = 0; nb < 2; ++nb) {
        const int col = gcol0 + nb * 32 + cl;
        cs[nb] = row_scales[col] * (1.0f / 127.0f);
        bb[nb] = bias[col];
    }
    const i32x16* accs[4][2] = {{&acc00, &acc01}, {&acc10, &acc11},
                                {&acc20, &acc21}, {&acc30, &acc31}};
#pragma unroll
    for (int mb = 0; mb < 4; ++mb) {
#pragma unroll
        for (int reg = 0; reg < 16; ++reg) {
            const int rloc = wr * 128 + mb * 32 + (reg & 3) + 8 * (reg >> 2) + rg4;
            const float tsv = ts[rloc];
            float* orow = out + (size_t)(bm * 256 + rloc) * N_OUT + gcol0 + cl;
#pragma unroll
            for (int nb = 0; nb < 2; ++nb) {
                const int a = (*accs[mb][nb])[reg];
                orow[nb * 32] = (float)a * tsv * cs[nb] + bb[nb];
            }
        }
    }
}

// ---------------- launch ----------------

extern "C" void kernel_launch(void* const* d_in, const int* in_sizes, int n_in,
                              void* d_out, int out_size, void* d_ws, size_t ws_size,
                              hipStream_t stream) {
    const float* x = (const float*)d_in[0];
    const int* wq = (const int*)d_in[1];
    const float* row_scales = (const float*)d_in[2];
    const float* bias = (const float*)d_in[3];
    float* out = (float*)d_out;

    signed char* xq8 = (signed char*)d_ws;                       // 32 MiB row-major
    signed char* xqF = xq8 + (size_t)M_TOK * K_IN;               // 32 MiB frag-tiled
    signed char* wqF = xqF + (size_t)M_TOK * K_IN;               // 16 MiB frag-tiled
    float* tok_scale = (float*)(wqF + (size_t)N_OUT * K_IN);     // 32 KiB
    (void)ws_size;

    quant_x_kernel<<<M_TOK, 256, 0, stream>>>(x, xq8, tok_scale);
    pack_w_frag_kernel<<<1024, 256, 0, stream>>>(wq, wqF);
    retile_x_kernel<<<1024, 256, 0, stream>>>(xq8, xqF);

    const int nblocks = (M_TOK / 256) * (N_OUT / 256);  // 512
    qgemm_i8f_kernel<<<nblocks, 512, 0, stream>>>(
        xqF, wqF, tok_scale, row_scales, bias, out);
}